// Round 4
// baseline (272.845 us; speedup 1.0000x reference)
//
#include <hip/hip_runtime.h>

#define ROW_L 32000
#define NT    256
#define NV    (ROW_L / 4)   // 8000 float4 per row
#define UF    8             // float4 in one load batch (per wave)

typedef float f32x4 __attribute__((ext_vector_type(4)));

// Issue a batch of UF coalesced float4 loads (lane-strided), pin issue order.
#define LOADB(dst, kk) do {                                                  \
    const int base_ = (kk) * (UF * 64) + lane;                               \
    _Pragma("unroll")                                                        \
    for (int u = 0; u < UF; ++u) dst[u] = q[base_ + u * 64];                 \
    __builtin_amdgcn_sched_barrier(0);                                       \
} while (0)

// Consume a batch: running first-max argmax; the conf_best wave also streams
// the values to out (bit-exact speculative copy, no extra reads).
#define CONSUME(src, kk) do {                                                \
    const int base_ = (kk) * (UF * 64) + lane;                               \
    _Pragma("unroll")                                                        \
    for (int u = 0; u < UF; ++u) {                                           \
        const f32x4 v = src[u];                                              \
        const int bi = (base_ + u * 64) * 4;                                 \
        if (v.x > m) { m = v.x; mi = bi + 0; }                               \
        if (v.y > m) { m = v.y; mi = bi + 1; }                               \
        if (v.z > m) { m = v.z; mi = bi + 2; }                               \
        if (v.w > m) { m = v.w; mi = bi + 3; }                               \
        if (do_store) __builtin_nontemporal_store(v, &qo[base_ + u * 64]);   \
    }                                                                        \
} while (0)

__global__ __launch_bounds__(NT) void oracle_best_expert_kernel(
    const int* __restrict__ labels,
    const float* __restrict__ g0,
    const float* __restrict__ g1,
    const float* __restrict__ g2,
    const float* __restrict__ g3,
    float* __restrict__ out)
{
    const int b = blockIdx.x;
    const size_t row = (size_t)b * ROW_L;
    const float* __restrict__ p0 = g0 + row;
    const float* __restrict__ p1 = g1 + row;
    const float* __restrict__ p2 = g2 + row;
    const float* __restrict__ p3 = g3 + row;

    const int tid  = threadIdx.x;
    const int wave = tid >> 6;
    const int lane = tid & 63;

    __shared__ float s_labv[4];   // logits[e][label]
    __shared__ float s_max[4];
    __shared__ int   s_idx[4];
    __shared__ int   s_fix;       // corrective expert (-1 = speculation held)

    // This wave's expert row (select chain, no runtime-indexed array).
    const float* __restrict__ pw = (wave == 0) ? p0 :
                                   (wave == 1) ? p1 :
                                   (wave == 2) ? p2 : p3;
    const f32x4* __restrict__ q  = (const f32x4*)pw;
    f32x4* __restrict__       qo = (f32x4*)(out + row);

    // --- Preamble: label logits -> conf_best (speculative best expert) ---
    const int lab = labels[b];
    if (lane == 0) s_labv[wave] = pw[lab];
    __syncthreads();
    const float c0 = s_labv[0], c1 = s_labv[1], c2 = s_labv[2], c3 = s_labv[3];
    int cb = 0; float bm = c0;                       // first-max tie-break
    if (c1 > bm) { bm = c1; cb = 1; }
    if (c2 > bm) { bm = c2; cb = 2; }
    if (c3 > bm) { bm = c3; cb = 3; }
    const bool do_store = (wave == cb);              // wave-uniform

    // --- Fused scan (+ speculative copy), ping-pong double-buffered ---
    // Lane visits strictly increasing indices -> strict '>' keeps FIRST max.
    float m  = -__builtin_inff();
    int   mi = 0;

    f32x4 Abuf[UF], Bbuf[UF];
    LOADB(Abuf, 0);
#pragma unroll 1
    for (int k = 0; k < 14; k += 2) {
        LOADB(Bbuf, k + 1);
        CONSUME(Abuf, k);
        LOADB(Abuf, k + 2);
        CONSUME(Bbuf, k + 1);
    }
    CONSUME(Abuf, 14);
    {   // tail: 8000 - 15*512 = 320 float4 (5 per lane)
        const int base_ = 15 * (UF * 64) + lane;     // 7680 + lane
        f32x4 T[5];
#pragma unroll
        for (int u = 0; u < 5; ++u) T[u] = q[base_ + u * 64];
#pragma unroll
        for (int u = 0; u < 5; ++u) {
            const f32x4 v = T[u];
            const int bi = (base_ + u * 64) * 4;
            if (v.x > m) { m = v.x; mi = bi + 0; }
            if (v.y > m) { m = v.y; mi = bi + 1; }
            if (v.z > m) { m = v.z; mi = bi + 2; }
            if (v.w > m) { m = v.w; mi = bi + 3; }
            if (do_store) __builtin_nontemporal_store(v, &qo[base_ + u * 64]);
        }
    }

    // 64-lane reduce; equal value -> smaller index (first occurrence).
#pragma unroll
    for (int off = 32; off >= 1; off >>= 1) {
        const float ov = __shfl_down(m, off, 64);
        const int   oi = __shfl_down(mi, off, 64);
        if (ov > m || (ov == m && oi < mi)) { m = ov; mi = oi; }
    }
    if (lane == 0) { s_max[wave] = m; s_idx[wave] = mi; }
    __syncthreads();

    // --- Resolve: first correct expert, else conf_best (already written) ---
    if (tid == 0) {
        int best = -1;
#pragma unroll
        for (int e = 0; e < 4; ++e)
            if (best < 0 && s_idx[e] == lab) best = e;
        if (best < 0) best = cb;
        s_fix = (best == cb) ? -1 : best;
    }
    __syncthreads();

    // --- Rare correction (~0.01% of rows): overwrite with the true winner ---
    const int fx = s_fix;
    if (fx >= 0) {
        const f32x4* __restrict__ src = (const f32x4*)((fx == 0) ? p0 :
                                                       (fx == 1) ? p1 :
                                                       (fx == 2) ? p2 : p3);
        for (int i = tid; i < NV; i += NT)
            __builtin_nontemporal_store(src[i], &qo[i]);
    }
}

extern "C" void kernel_launch(void* const* d_in, const int* in_sizes, int n_in,
                              void* d_out, int out_size, void* d_ws, size_t ws_size,
                              hipStream_t stream) {
    const int*   labels = (const int*)d_in[0];
    const float* g0     = (const float*)d_in[1];
    const float* g1     = (const float*)d_in[2];
    const float* g2     = (const float*)d_in[3];
    const float* g3     = (const float*)d_in[4];
    float*       out    = (float*)d_out;

    const int B = in_sizes[0];  // 2048 rows
    oracle_best_expert_kernel<<<B, NT, 0, stream>>>(labels, g0, g1, g2, g3, out);
}

// Round 5
// 260.168 us; speedup vs baseline: 1.0487x; 1.0487x over previous
//
#include <hip/hip_runtime.h>

#define ROW_L 32000
#define NT    512            // 8 waves: wave = expert*2 + half
#define NV    (ROW_L / 4)    // 8000 float4 per row
#define HV    4000           // float4 per half-row
#define UF    8              // float4 per load batch per wave

typedef float f32x4 __attribute__((ext_vector_type(4)));

// Batch of UF coalesced float4 loads from this wave's half-row region.
#define LOADB(dst, kk) do {                                                  \
    const int base_ = r0 + (kk) * (UF * 64) + lane;                          \
    _Pragma("unroll")                                                        \
    for (int u = 0; u < UF; ++u) dst[u] = q[base_ + u * 64];                 \
    __builtin_amdgcn_sched_barrier(0);                                       \
} while (0)

// Consume a batch: running first-max argmax (absolute column index); the
// conf_best expert's waves also stream values to out (speculative copy).
#define CONSUME(src, kk) do {                                                \
    const int base_ = r0 + (kk) * (UF * 64) + lane;                          \
    _Pragma("unroll")                                                        \
    for (int u = 0; u < UF; ++u) {                                           \
        const f32x4 v = src[u];                                              \
        const int fi = base_ + u * 64;                                       \
        const int bi = fi * 4;                                               \
        if (v.x > m) { m = v.x; mi = bi + 0; }                               \
        if (v.y > m) { m = v.y; mi = bi + 1; }                               \
        if (v.z > m) { m = v.z; mi = bi + 2; }                               \
        if (v.w > m) { m = v.w; mi = bi + 3; }                               \
        if (do_store) qo[fi] = v;                                            \
    }                                                                        \
} while (0)

__global__ __launch_bounds__(NT) void oracle_best_expert_kernel(
    const int* __restrict__ labels,
    const float* __restrict__ g0,
    const float* __restrict__ g1,
    const float* __restrict__ g2,
    const float* __restrict__ g3,
    float* __restrict__ out)
{
    const int b = blockIdx.x;
    const size_t row = (size_t)b * ROW_L;
    const float* __restrict__ p0 = g0 + row;
    const float* __restrict__ p1 = g1 + row;
    const float* __restrict__ p2 = g2 + row;
    const float* __restrict__ p3 = g3 + row;

    const int tid  = threadIdx.x;
    const int wave = tid >> 6;        // 0..7
    const int lane = tid & 63;
    const int e    = wave >> 1;       // this wave's expert
    const int h    = wave & 1;        // this wave's half-row
    const int r0   = h * HV;          // float4 region base

    __shared__ float s_max[8];
    __shared__ int   s_idx[8];
    __shared__ int   s_fix;           // corrective expert (-1 = spec held)

    const float* __restrict__ pw = (e == 0) ? p0 :
                                   (e == 1) ? p1 :
                                   (e == 2) ? p2 : p3;
    const f32x4* __restrict__ q  = (const f32x4*)pw;
    f32x4* __restrict__       qo = (f32x4*)(out + row);

    // Label logits -> conf_best (every thread; same-address lanes coalesce).
    const int lab = labels[b];
    const float c0 = p0[lab], c1 = p1[lab], c2 = p2[lab], c3 = p3[lab];
    int cb = 0; float bm = c0;                   // first-max tie-break
    if (c1 > bm) { bm = c1; cb = 1; }
    if (c2 > bm) { bm = c2; cb = 2; }
    if (c3 > bm) { bm = c3; cb = 3; }
    const bool do_store = (e == cb);             // wave-uniform

    // Fused scan (+ speculative copy) of this wave's half-row: 4000 float4 =
    // 7 batches of 512 + 6 lane-rounds + 32. Lane indices strictly increase,
    // so strict '>' keeps the FIRST max (jnp.argmax tie rule).
    float m  = -__builtin_inff();
    int   mi = 0;

    f32x4 Abuf[UF], Bbuf[UF];
    LOADB(Abuf, 0);
#pragma unroll 1
    for (int k = 0; k < 6; k += 2) {
        LOADB(Bbuf, k + 1);
        CONSUME(Abuf, k);
        LOADB(Abuf, k + 2);
        CONSUME(Bbuf, k + 1);
    }
    CONSUME(Abuf, 6);
    {   // tail: 416 float4 = 6 full lane-rounds + 32
        const int base_ = r0 + 7 * (UF * 64) + lane;   // r0 + 3584 + lane
        f32x4 T[6];
#pragma unroll
        for (int u = 0; u < 6; ++u) T[u] = q[base_ + u * 64];
#pragma unroll
        for (int u = 0; u < 6; ++u) {
            const f32x4 v = T[u];
            const int fi = base_ + u * 64;
            const int bi = fi * 4;
            if (v.x > m) { m = v.x; mi = bi + 0; }
            if (v.y > m) { m = v.y; mi = bi + 1; }
            if (v.z > m) { m = v.z; mi = bi + 2; }
            if (v.w > m) { m = v.w; mi = bi + 3; }
            if (do_store) qo[fi] = v;
        }
        if (lane < 32) {
            const int fi = r0 + 3968 + lane;
            const f32x4 v = q[fi];
            const int bi = fi * 4;
            if (v.x > m) { m = v.x; mi = bi + 0; }
            if (v.y > m) { m = v.y; mi = bi + 1; }
            if (v.z > m) { m = v.z; mi = bi + 2; }
            if (v.w > m) { m = v.w; mi = bi + 3; }
            if (do_store) qo[fi] = v;
        }
    }

    // 64-lane reduce; equal value -> smaller index (first occurrence).
#pragma unroll
    for (int off = 32; off >= 1; off >>= 1) {
        const float ov = __shfl_down(m, off, 64);
        const int   oi = __shfl_down(mi, off, 64);
        if (ov > m || (ov == m && oi < mi)) { m = ov; mi = oi; }
    }
    if (lane == 0) { s_max[wave] = m; s_idx[wave] = mi; }
    __syncthreads();

    // Resolve: combine halves (half1 indices all larger -> '>' keeps first
    // max), then first correct expert, else conf_best (already written).
    if (tid == 0) {
        int best = -1;
#pragma unroll
        for (int ee = 0; ee < 4; ++ee) {
            const int ix = (s_max[2 * ee + 1] > s_max[2 * ee])
                               ? s_idx[2 * ee + 1] : s_idx[2 * ee];
            if (best < 0 && ix == lab) best = ee;
        }
        if (best < 0) best = cb;
        s_fix = (best == cb) ? -1 : best;
    }
    __syncthreads();

    // Rare correction (~0.01% of rows): overwrite with the true winner.
    const int fx = s_fix;
    if (fx >= 0) {
        const f32x4* __restrict__ src = (const f32x4*)((fx == 0) ? p0 :
                                                       (fx == 1) ? p1 :
                                                       (fx == 2) ? p2 : p3);
        for (int i = tid; i < NV; i += NT) qo[i] = src[i];
    }
}

extern "C" void kernel_launch(void* const* d_in, const int* in_sizes, int n_in,
                              void* d_out, int out_size, void* d_ws, size_t ws_size,
                              hipStream_t stream) {
    const int*   labels = (const int*)d_in[0];
    const float* g0     = (const float*)d_in[1];
    const float* g1     = (const float*)d_in[2];
    const float* g2     = (const float*)d_in[3];
    const float* g3     = (const float*)d_in[4];
    float*       out    = (float*)d_out;

    const int B = in_sizes[0];  // 2048 rows
    oracle_best_expert_kernel<<<B, NT, 0, stream>>>(labels, g0, g1, g2, g3, out);
}